// Round 7
// baseline (380.510 us; speedup 1.0000x reference)
//
#include <hip/hip_runtime.h>

// image2patch: out[b, i*126+j, r*6+c] = x[b, 0, 2*i + r, 2*j + c]
// IMAGE_SIZE=256, PSIZE=6, STRIDE=2, NPOS=126, BATCH=128, fp32.
//
// R7 DISCRIMINATOR: kernel body identical to R6; launched TWICE (idempotent
// -> correct). dur(R7) - dur(R6) = true kernel duration, resolving the
// fixed-overhead ambiguity that four neutral rounds couldn't:
//   dur ~440 -> kernel ~120us (2x over write floor, keep optimizing)
//   dur ~380 -> kernel ~60us (at floor; residual is harness fill -> ROOFLINE)

#define IMG 256
#define PSZ 6
#define NPOS 126
#define BATCHN 128
#define NB 6                        // bands (patch-rows) per block
#define NGROUPS 21                  // 126 / 6, exact
#define TROWS 16                    // 2*NB + 4 image rows staged
#define LDSW 258                    // even pad: 8B-aligned pairs, W/2 % 16 == 1
#define VECS_PER_BAND 1134          // 126 patches * 36 floats / 4
#define NITER 5                     // ceil(1134/256); n=4 valid iff t<110

typedef float fvec4 __attribute__((ext_vector_type(4)));
typedef float fvec2 __attribute__((ext_vector_type(2)));

__global__ __launch_bounds__(256) void image2patch_kernel(
    const float* __restrict__ x, float* __restrict__ out) {
  __shared__ float tile[TROWS * LDSW];   // 16.1 KB

  const int blk = blockIdx.x;            // b * 21 + g
  const int b = blk / NGROUPS;
  const int g = blk - b * NGROUPS;
  const int i0 = g * NB;
  const int t = threadIdx.x;

  // ---- stage image rows 12g..12g+15: thread t = column t of every row ----
  const float* src = x + (size_t)b * (IMG * IMG) + (size_t)(12 * g) * IMG;
  #pragma unroll
  for (int w = 0; w < TROWS; ++w) {
    tile[w * LDSW + t] = src[w * IMG + t];
  }

  // ---- hoist gather offsets: two b64 pair-offsets per float4, band-indep.
  int off0[NITER], off1[NITER];
  #pragma unroll
  for (int n = 0; n < NITER; ++n) {
    const int q = t + n * 256;          // output float4 index within a band
    const int j = q / 9;                // patch column (9 float4 per patch)
    const int s = q - 9 * j;
    const int k0 = 4 * s;               // even; pairs (k0,k0+1),(k0+2,k0+3)
    const int r0 = k0 / PSZ,       c0 = k0 - PSZ * r0;
    const int r1 = (k0 + 2) / PSZ, c1 = (k0 + 2) - PSZ * r1;
    off0[n] = r0 * LDSW + 2 * j + c0;   // even float offset -> 8B-aligned
    off1[n] = r1 * LDSW + 2 * j + c1;
  }

  __syncthreads();

  // ---- emit 6 bands: hot loop = 2 ds_read_b64 + 1 global_store_dwordx4 ----
  #pragma unroll
  for (int band = 0; band < NB; ++band) {
    const float* tb = &tile[(2 * band) * LDSW];
    fvec4* outp = reinterpret_cast<fvec4*>(
        out + ((size_t)b * (NPOS * NPOS) + (size_t)(i0 + band) * NPOS) * (PSZ * PSZ));
    #pragma unroll
    for (int n = 0; n < NITER; ++n) {
      const int q = t + n * 256;
      if (q < VECS_PER_BAND) {          // only n=4 masks (t<110)
        const fvec2 p0 = *reinterpret_cast<const fvec2*>(tb + off0[n]);
        const fvec2 p1 = *reinterpret_cast<const fvec2*>(tb + off1[n]);
        fvec4 v;
        v.x = p0.x; v.y = p0.y; v.z = p1.x; v.w = p1.y;
        outp[q] = v;
      }
    }
  }
}

extern "C" void kernel_launch(void* const* d_in, const int* in_sizes, int n_in,
                              void* d_out, int out_size, void* d_ws, size_t ws_size,
                              hipStream_t stream) {
  const float* x = (const float*)d_in[0];
  float* out = (float*)d_out;
  // Launched twice on purpose: idempotent writes; the bench-time delta vs
  // the single-launch round measures the kernel's true duration.
  image2patch_kernel<<<BATCHN * NGROUPS, 256, 0, stream>>>(x, out);
  image2patch_kernel<<<BATCHN * NGROUPS, 256, 0, stream>>>(x, out);
}